// Round 15
// baseline (17357.684 us; speedup 1.0000x reference)
//
#include <hip/hip_runtime.h>
#include <hip/hip_fp16.h>

#define BB 8
#define SS 2048
#define EE 1024
#define NHH 4
#define DHH 256

typedef _Float16 f16x2 __attribute__((ext_vector_type(2)));
typedef _Float16 f16x8 __attribute__((ext_vector_type(8)));
typedef float f32x4 __attribute__((ext_vector_type(4)));

__device__ __forceinline__ __half2 u2h2(unsigned int u) {
  union { unsigned int u; __half2 h; } c; c.u = u; return c.h;
}
__device__ __forceinline__ unsigned int h2u(__half2 h) {
  union { unsigned int u; __half2 h; } c; c.h = h; return c.u;
}
__device__ __forceinline__ unsigned int packh2(float a, float b) {
  return h2u(__floats2half2_rn(a, b));
}

// ---------------------------------------------------------------------------
// Gates projection GEMM via MFMA f16 (round-10 verbatim, verified).
// Output: gx f16, layout [S][B][NH][4*DH] = [i f z o]
// ---------------------------------------------------------------------------
__global__ __launch_bounds__(256) void gates_gemm(
    const float* __restrict__ x, const float* __restrict__ conv_w,
    const float* __restrict__ conv_b,
    const float* __restrict__ fgw, const float* __restrict__ igw,
    const float* __restrict__ zgw, const float* __restrict__ ogw,
    __half* __restrict__ gx)
{
  __shared__ float Xs[8][11][33];
  __shared__ __half As[64][40];
  __shared__ __half Bs[64][40];

  const int tid = threadIdx.x;
  const int mt = blockIdx.x;
  const int nt = blockIdx.y;
  const int p  = blockIdx.z;
  const int h  = p >> 1, pair = p & 1;
  const int s0 = mt << 3;
  const int n0 = nt << 6;

  const float* W0 = pair ? zgw : fgw;
  const float* W1 = pair ? ogw : igw;

  const int w = tid >> 6, l = tid & 63;
  const int lrow = l & 15, kq = l >> 4;
  const int koff = kq << 3;

  f32x4 acc[4] = {};

  for (int d0 = 0; d0 < DHH; d0 += 32) {
    const int ebase = h * DHH + d0;

    if (pair == 0) {
      for (int i = tid; i < 8 * 11 * 32; i += 256) {
        int kk = i & 31, rest = i >> 5;
        int b = rest / 11, si = rest - b * 11;
        int sg = s0 - 3 + si;
        float v = 0.f;
        if (sg >= 0) v = x[((size_t)b * SS + sg) * EE + ebase + kk];
        Xs[b][si][kk] = v;
      }
      __syncthreads();
      for (int i = tid; i < 64 * 32; i += 256) {
        int kk = i & 31, r = i >> 5;
        int sl = r >> 3, b = r & 7;
        int e = ebase + kk;
        float xc = conv_b[e];
        xc = fmaf(Xs[b][sl + 0][kk], conv_w[0 * EE + e], xc);
        xc = fmaf(Xs[b][sl + 1][kk], conv_w[1 * EE + e], xc);
        xc = fmaf(Xs[b][sl + 2][kk], conv_w[2 * EE + e], xc);
        xc = fmaf(Xs[b][sl + 3][kk], conv_w[3 * EE + e], xc);
        float sg = 1.f / (1.f + __expf(-xc));
        As[r][kk] = __float2half(xc * sg);
      }
    } else {
      for (int i = tid; i < 64 * 32; i += 256) {
        int kk = i & 31, r = i >> 5;
        int sl = r >> 3, b = r & 7;
        As[r][kk] = __float2half(x[((size_t)b * SS + s0 + sl) * EE + ebase + kk]);
      }
    }
    for (int i = tid; i < 64 * 32; i += 256) {
      int k = i & 31, col = i >> 5;
      int o = n0 + col;
      const float* Wp = (o < 256) ? W0 : W1;
      int oo = o & 255;
      Bs[col][k] = __float2half(Wp[((size_t)h * DHH + oo) * DHH + d0 + k]);
    }
    __syncthreads();

    f16x8 bfrag = *(const f16x8*)&Bs[w * 16 + lrow][koff];
#pragma unroll
    for (int mtl = 0; mtl < 4; ++mtl) {
      f16x8 afrag = *(const f16x8*)&As[mtl * 16 + lrow][koff];
      acc[mtl] = __builtin_amdgcn_mfma_f32_16x16x32_f16(afrag, bfrag, acc[mtl], 0, 0, 0);
    }
    __syncthreads();
  }

#pragma unroll
  for (int mtl = 0; mtl < 4; ++mtl) {
#pragma unroll
    for (int j = 0; j < 4; ++j) {
      int row_loc = mtl * 16 + kq * 4 + j;
      int grow = s0 * 8 + row_loc;
      int colg = n0 + w * 16 + lrow;
      gx[(size_t)grow * 4096 + h * 1024 + pair * 512 + colg] = __float2half(acc[mtl][j]);
    }
  }
}

// ---------------------------------------------------------------------------
// sLSTM scan v6b: chains batched over MFMA M-dim, 8 CUs per head.
// grid = 32 WGs x 512 thr. WG = (slice s = bid>>2, head h = bid&3).
// Fix vs v6 (round 14): ybuf slot = 128 u32 (a y-slice is 32 dims x 8 chains
// = 256 f16 = 128 u32; v6 sized slots at 32 u32 -> OOB publish + partial
// gather). Flag store RELEASE; __threadfence() before gather.
// ybuf: [32 wg][4 slot][128 u32]; yflag: [32 wg][4 slot].
// ---------------------------------------------------------------------------
__global__ __launch_bounds__(512)
void slstm_scan6(
    const float* __restrict__ rk,    // (NH, DH, 4*DH)
    const float* __restrict__ rb,    // (NH, 4, DH)
    const __half* __restrict__ gx,   // [S][B][NH][1024]
    float* __restrict__ out,         // (B, S, E)
    unsigned int* __restrict__ ybuf, // [32][4][128]
    unsigned int* __restrict__ yflag)// [32][4]
{
  __shared__ __half ylds[8][272];        // chain-major y, padded rows (544 B, 16B-aligned)
  __shared__ float rawlds[4][32][8];     // [gate][dloc][chain]
  __shared__ int fw;                     // freewheel escape flag

  const int t = threadIdx.x;
  const int w = t >> 6, l = t & 63;
  const int lrow = l & 15, lkq = l >> 4;
  const int s = blockIdx.x >> 2, h = blockIdx.x & 3;
  const int wg = s * 4 + h;
  const float* Rh = rk + (size_t)h * DHH * 1024;

  // wave's 16 columns: gate gw, half hw
  const int gw = w >> 1, hw = w & 1;
  const int colg = gw * 256 + s * 32 + hw * 16 + lrow;

  // B fragments: 8 k-tiles, register-resident (32 dwords/lane)
  f16x8 wB[8];
#pragma unroll
  for (int kt = 0; kt < 8; ++kt) {
    f16x8 f;
#pragma unroll
    for (int i = 0; i < 8; ++i) {
      const int k = kt * 32 + lkq * 8 + i;
      f[i] = (_Float16)Rh[(size_t)k * 1024 + colg];
    }
    wB[kt] = f;
  }

  // state-thread mapping: t<256 -> (dloc, chain bs)
  const int dloc = (t >> 3) & 31, bs = t & 7;
  const int dglob = s * 32 + dloc;
  float rbv[4] = {};
  if (t < 256) {
#pragma unroll
    for (int g = 0; g < 4; ++g) rbv[g] = rb[h * 1024 + g * 256 + dglob];
  }

  for (int i = t; i < 8 * 272; i += 512) ((__half*)ylds)[i] = __float2half(0.f);
  if (t == 0) fw = 0;
  __syncthreads();

  const size_t gxstep = (size_t)BB * NHH * 1024;
  const __half* gpz = gx + ((size_t)bs * NHH + h) * 1024;
  float cx[4] = {};
  __half nh[4] = {};
  if (t < 256) {
#pragma unroll
    for (int g = 0; g < 4; ++g) cx[g] = __half2float(gpz[g * 256 + dglob]);
  }

  float cst = 0.f, nstt = 0.f, mst = 0.f;

  for (int st = 0; st < SS; ++st) {
    const int slot = st & 3;
    // prefetch next step's gate inputs (drained by B2's vmcnt, used next iter)
    if (t < 256) {
      const int sp = (st + 1 < SS) ? st + 1 : st;
#pragma unroll
      for (int g = 0; g < 4; ++g) nh[g] = gpz[(size_t)sp * gxstep + g * 256 + dglob];
    }

    // ---- matvec: 8 MFMAs; A rows = chains from ylds ----
    f32x4 acc = {};
#pragma unroll
    for (int kt = 0; kt < 8; ++kt) {
      f16x8 A = *(const f16x8*)&ylds[lrow & 7][kt * 32 + lkq * 8];
      acc = __builtin_amdgcn_mfma_f32_16x16x32_f16(A, wB[kt], acc, 0, 0, 0);
    }
    // D: col=lrow, rows (lkq*4..+3) = chains; lanes l<32 hold valid rows 0..7
    if (l < 32) {
      *(f32x4*)&rawlds[gw][hw * 16 + lrow][lkq * 4] = acc;
    }
    __syncthreads();                                   // B1: raw ready

    // ---- state for own 32 dims x 8 chains ----
    float y = 0.f;
    if (t < 256) {
      float iv = rawlds[0][dloc][bs] + cx[0] + rbv[0];
      float fv = rawlds[1][dloc][bs] + cx[1] + rbv[1];
      float zv = rawlds[2][dloc][bs] + cx[2] + rbv[2];
      float ov = rawlds[3][dloc][bs] + cx[3] + rbv[3];

      float ea = __expf(-fabsf(fv));
      float ls = fminf(fv, 0.f) - __logf(1.f + ea);    // log_sigmoid(fv)
      float lfm = mst + ls;
      float mn = fmaxf(iv, lfm);
      float ig = __expf(iv - mn);
      float fg = __expf(lfm - mn);
      float pz = __expf(-2.f * fabsf(zv));
      float tm = __fdividef(1.f - pz, 1.f + pz);
      float th = (zv < 0.f) ? -tm : tm;                // tanh(zv)
      cst = fg * cst + ig * th;
      nstt = fg * nstt + ig;
      float og = __fdividef(1.f, 1.f + __expf(-ov));   // sigmoid(ov)
      y = og * __fdividef(cst, nstt);
      mst = mn;
      ylds[bs][dglob] = __float2half(y);               // own dims locally
    }
    // publish y-slice: chain pairs packed to u32, relaxed agent (MALL) stores
    float ypart = __shfl_down(y, 1);
    if (t < 256 && (bs & 1) == 0) {
      unsigned int u = packh2(y, ypart);
      int i = dloc * 4 + (bs >> 1);                    // 0..127
      __hip_atomic_store(&ybuf[wg * 512 + slot * 128 + i], u,
                         __ATOMIC_RELAXED, __HIP_MEMORY_SCOPE_AGENT);
    }
    __syncthreads();                                   // B2: drains vmcnt in all waves
    if (t == 0)
      __hip_atomic_store(&yflag[wg * 4 + slot], (unsigned)(st + 1),
                         __ATOMIC_RELEASE, __HIP_MEMORY_SCOPE_AGENT);
    // out row (fire-and-forget, drained by next step's B2)
    if (t < 256)
      out[((size_t)bs * SS + st) * EE + h * DHH + dglob] = y;

    // ---- spin on 7 peers (waves 1..7, lane 0), ring-4 stamps ----
    if (w >= 1 && l == 0 && fw == 0) {
      const int ps = (w - 1 < s) ? (w - 1) : w;
      const unsigned want = (unsigned)(st + 1);
      int it = 0;
      while (__hip_atomic_load(&yflag[(ps * 4 + h) * 4 + slot],
                               __ATOMIC_ACQUIRE, __HIP_MEMORY_SCOPE_AGENT) < want) {
        __builtin_amdgcn_s_sleep(1);
        if (++it > (1 << 20)) { fw = 1; break; }       // escape: no hangs
      }
    }
    __syncthreads();                                   // B3: all peers ready
    __threadfence();                                   // order gather loads

    // ---- gather peers' y slices: 7 peers x 128 u32 ----
    for (int idx = t; idx < 7 * 128; idx += 512) {
      const int p = idx >> 7;
      const int ps = (p < s) ? p : p + 1;
      const int i = idx & 127;
      unsigned int u = __hip_atomic_load(&ybuf[(ps * 4 + h) * 512 + slot * 128 + i],
                                         __ATOMIC_RELAXED, __HIP_MEMORY_SCOPE_AGENT);
      __half2 hh = u2h2(u);
      const int dl = i >> 2, b0 = (i & 3) * 2;
      ylds[b0][ps * 32 + dl]     = __low2half(hh);
      ylds[b0 + 1][ps * 32 + dl] = __high2half(hh);
    }
    __syncthreads();                                   // B4: ylds complete
#pragma unroll
    for (int g = 0; g < 4; ++g) cx[g] = __half2float(nh[g]);
  }
}

// ---------------------------------------------------------------------------
// GroupNorm over DH per (b,s,h), in place on out. One wave = one head.
// ---------------------------------------------------------------------------
__global__ __launch_bounds__(256) void groupnorm(
    float* __restrict__ y, const float* __restrict__ gnw)
{
  const int row = blockIdx.x;
  const int t = threadIdx.x;
  float4 v = ((const float4*)y)[(size_t)row * 256 + t];
  float s = v.x + v.y + v.z + v.w;
  float q = v.x * v.x + v.y * v.y + v.z * v.z + v.w * v.w;
#pragma unroll
  for (int mask = 1; mask < 64; mask <<= 1) {
    s += __shfl_xor(s, mask, 64);
    q += __shfl_xor(q, mask, 64);
  }
  float mu = s * (1.f / 256.f);
  float var = q * (1.f / 256.f) - mu * mu;
  float rs = rsqrtf(var + 1e-5f);
  float4 g = ((const float4*)gnw)[t];
  float4 o;
  o.x = (v.x - mu) * rs * g.x;
  o.y = (v.y - mu) * rs * g.y;
  o.z = (v.z - mu) * rs * g.z;
  o.w = (v.w - mu) * rs * g.w;
  ((float4*)y)[(size_t)row * 256 + t] = o;
}

extern "C" void kernel_launch(void* const* d_in, const int* in_sizes, int n_in,
                              void* d_out, int out_size, void* d_ws, size_t ws_size,
                              hipStream_t stream) {
  const float* x      = (const float*)d_in[0];
  const float* conv_w = (const float*)d_in[1];
  const float* conv_b = (const float*)d_in[2];
  const float* fgw    = (const float*)d_in[3];
  const float* igw    = (const float*)d_in[4];
  const float* zgw    = (const float*)d_in[5];
  const float* ogw    = (const float*)d_in[6];
  const float* rk     = (const float*)d_in[7];
  const float* rb     = (const float*)d_in[8];
  const float* gnw    = (const float*)d_in[9];
  float* out = (float*)d_out;

  __half* gx = (__half*)d_ws;                                            // 134217728 B
  unsigned int* ybuf  = (unsigned int*)((char*)d_ws + 134217728);        // 65536 B
  unsigned int* yflag = (unsigned int*)((char*)d_ws + 134217728 + 65536);// 512 B

  (void)hipMemsetAsync(ybuf, 0, 65536 + 512, stream);

  dim3 g1(256, 8, 8);
  gates_gemm<<<g1, 256, 0, stream>>>(x, conv_w, conv_b, fgw, igw, zgw, ogw, gx);

  slstm_scan6<<<32, 512, 0, stream>>>(rk, rb, gx, out, ybuf, yflag);

  groupnorm<<<BB * SS, 256, 0, stream>>>(out, gnw);
}

// Round 16
// 3946.700 us; speedup vs baseline: 4.3980x; 4.3980x over previous
//
#include <hip/hip_runtime.h>
#include <hip/hip_fp16.h>

#define BB 8
#define SS 2048
#define EE 1024
#define NHH 4
#define DHH 256

typedef _Float16 f16x2 __attribute__((ext_vector_type(2)));
typedef _Float16 f16x8 __attribute__((ext_vector_type(8)));
typedef float f32x4 __attribute__((ext_vector_type(4)));

__device__ __forceinline__ __half2 u2h2(unsigned int u) {
  union { unsigned int u; __half2 h; } c; c.u = u; return c.h;
}
__device__ __forceinline__ unsigned int h2u(__half2 h) {
  union { unsigned int u; __half2 h; } c; c.h = h; return c.u;
}
__device__ __forceinline__ f16x2 u2f(unsigned int u) {
  union { unsigned int u; f16x2 f; } c; c.u = u; return c.f;
}
__device__ __forceinline__ unsigned int pack2(float a, float b) {
  f16x2 f; f.x = (_Float16)a; f.y = (_Float16)b;
  union { f16x2 f; unsigned int u; } c; c.f = f; return c.u;
}
__device__ __forceinline__ float fdot2u(unsigned int w, unsigned int y, float acc) {
#if __has_builtin(__builtin_amdgcn_fdot2)
  return __builtin_amdgcn_fdot2(u2f(w), u2f(y), acc, false);
#else
  __half2 a = u2h2(w), b = u2h2(y);
  return acc + __low2float(a) * __low2float(b) + __high2float(a) * __high2float(b);
#endif
}

// ---------------------------------------------------------------------------
// Gates projection GEMM v2: pair-merged + 2x n-merged MFMA f16.
// grid (256 mt, 4 nt2, 4 h), block 256 (4 waves).
// Block computes BOTH pairs (pair0 = silu(conv(x)) @ [f/i], pair1 = x @ [z/o])
// for output cols [nt2*128, nt2*128+128) of each pair: x staged ONCE per
// block (was 4x across pair/nt splits in round-10) -> x refetch traffic /4.
// M=64 rows (8 s x 8 b), K=256 in 8 chunks of 32. 16 MFMA/chunk/wave.
// Output: gx f16, layout [S][B][NH][4*DH] = [i f z o]
// ---------------------------------------------------------------------------
__global__ __launch_bounds__(256) void gates_gemm2(
    const float* __restrict__ x, const float* __restrict__ conv_w,
    const float* __restrict__ conv_b,
    const float* __restrict__ fgw, const float* __restrict__ igw,
    const float* __restrict__ zgw, const float* __restrict__ ogw,
    __half* __restrict__ gx)
{
  __shared__ float Xs[8][11][33];      // [b][si][kk]  (halo 3)
  __shared__ __half As[2][64][40];     // [pair][row][k]
  __shared__ __half Bs[2][128][40];    // [pair][col][k]

  const int tid = threadIdx.x;
  const int mt  = blockIdx.x;          // 0..255
  const int nt2 = blockIdx.y;          // 0..3
  const int h   = blockIdx.z;          // 0..3
  const int s0  = mt << 3;             // seq offset (8 rows)
  const int n0  = nt2 << 7;            // 0..384

  // gate slice for this 128-col span (aligned: no straddle of 256)
  const float* W0 = (n0 < 256) ? fgw : igw;   // pair0
  const float* W1 = (n0 < 256) ? zgw : ogw;   // pair1
  const int oobase = n0 & 255;

  const int w = tid >> 6, l = tid & 63;
  const int lrow = l & 15, kq = l >> 4;
  const int koff = kq << 3;

  f32x4 acc[2][2][4] = {};

  for (int d0 = 0; d0 < DHH; d0 += 32) {
    const int ebase = h * DHH + d0;

    // ---- stage Xs (once!) + both B panels ----
    for (int i = tid; i < 8 * 11 * 32; i += 256) {
      int kk = i & 31, rest = i >> 5;
      int b = rest / 11, si = rest - b * 11;
      int sg = s0 - 3 + si;
      float v = 0.f;
      if (sg >= 0) v = x[((size_t)b * SS + sg) * EE + ebase + kk];
      Xs[b][si][kk] = v;
    }
    for (int i = tid; i < 2 * 128 * 32; i += 256) {
      int p = i >> 12;                 // 0..1
      int rem = i & 4095;
      int col = rem >> 5, k = rem & 31;
      const float* Wp = p ? W1 : W0;
      int oo = oobase + col;
      Bs[p][col][k] = __float2half(Wp[((size_t)h * DHH + oo) * DHH + d0 + k]);
    }
    __syncthreads();

    // ---- build both A panels from Xs ----
    for (int i = tid; i < 2 * 64 * 32; i += 256) {
      int p = i >> 11;
      int rem = i & 2047;
      int kk = rem & 31, r = rem >> 5;
      int sl = r >> 3, b = r & 7;
      if (p == 0) {
        int e = ebase + kk;
        float xc = conv_b[e];
        xc = fmaf(Xs[b][sl + 0][kk], conv_w[0 * EE + e], xc);
        xc = fmaf(Xs[b][sl + 1][kk], conv_w[1 * EE + e], xc);
        xc = fmaf(Xs[b][sl + 2][kk], conv_w[2 * EE + e], xc);
        xc = fmaf(Xs[b][sl + 3][kk], conv_w[3 * EE + e], xc);
        float sg = 1.f / (1.f + __expf(-xc));
        As[0][r][kk] = __float2half(xc * sg);
      } else {
        As[1][r][kk] = __float2half(Xs[b][sl + 3][kk]);
      }
    }
    __syncthreads();

    // ---- MFMA: wave w covers cols [w*32, w*32+32) of each pair ----
#pragma unroll
    for (int p = 0; p < 2; ++p) {
#pragma unroll
      for (int ct = 0; ct < 2; ++ct) {
        f16x8 bfrag = *(const f16x8*)&Bs[p][w * 32 + ct * 16 + lrow][koff];
#pragma unroll
        for (int mtl = 0; mtl < 4; ++mtl) {
          f16x8 afrag = *(const f16x8*)&As[p][mtl * 16 + lrow][koff];
          acc[p][ct][mtl] =
              __builtin_amdgcn_mfma_f32_16x16x32_f16(afrag, bfrag, acc[p][ct][mtl], 0, 0, 0);
        }
      }
    }
    __syncthreads();
  }

  // ---- epilogue: C/D col=lane&15, row=(lane>>4)*4+reg ----
#pragma unroll
  for (int p = 0; p < 2; ++p) {
#pragma unroll
    for (int ct = 0; ct < 2; ++ct) {
#pragma unroll
      for (int mtl = 0; mtl < 4; ++mtl) {
#pragma unroll
        for (int j = 0; j < 4; ++j) {
          int row_loc = mtl * 16 + kq * 4 + j;
          int grow = mt * 64 + row_loc;          // = s*8 + b
          int colg = n0 + w * 32 + ct * 16 + lrow;
          gx[(size_t)grow * 4096 + h * 1024 + p * 512 + colg] =
              __float2half(acc[p][ct][mtl][j]);
        }
      }
    }
  }
}

// ---------------------------------------------------------------------------
// sLSTM scan (round-6 verbatim — session-best 3.40 ms): one WG (512 thr)
// per chain (b,h). Lane-pair k-split; v_dot2 inner product; gates i,f,z in
// registers, gate o streamed from LDS; one barrier per step.
// Dynamic LDS: 131072 (wl4) + 1024 (ypub x2) = 132096 B
// ---------------------------------------------------------------------------
__global__
__attribute__((amdgpu_flat_work_group_size(512, 512), amdgpu_waves_per_eu(1)))
void slstm_scan(
    const float* __restrict__ rk,    // (NH, DH, 4*DH)
    const float* __restrict__ rb,    // (NH, 4, DH)
    const __half* __restrict__ gx,   // [S][B][NH][1024]
    float* __restrict__ out)         // (B, S, E)
{
  extern __shared__ unsigned char smem[];
  uint4* wl4   = (uint4*)smem;                      // [16][512]
  __half* ypub = (__half*)(smem + 131072);          // [2][256]

  const int t = threadIdx.x;
  const int b = blockIdx.x >> 2, h = blockIdx.x & 3;
  const int d = t >> 1, par = t & 1;
  const int kbase = par << 7;                       // 0 or 128
  const float* Rh = rk + (size_t)h * DHH * 1024;

  // weights: gates 0..2 (i,f,z) in registers, gate 3 (o) in LDS
  unsigned int wv[3][64];
#pragma unroll
  for (int g = 0; g < 3; ++g) {
    const int col = g * 256 + d;
#pragma unroll
    for (int pp = 0; pp < 64; ++pp) {
      int k = kbase + 2 * pp;
      wv[g][pp] = pack2(Rh[(size_t)k * 1024 + col], Rh[(size_t)(k + 1) * 1024 + col]);
    }
  }
  {
    const int col = 3 * 256 + d;
    for (int q = 0; q < 16; ++q) {
      uint4 u;
      int k = kbase + 8 * q;
      u.x = pack2(Rh[(size_t)(k + 0) * 1024 + col], Rh[(size_t)(k + 1) * 1024 + col]);
      u.y = pack2(Rh[(size_t)(k + 2) * 1024 + col], Rh[(size_t)(k + 3) * 1024 + col]);
      u.z = pack2(Rh[(size_t)(k + 4) * 1024 + col], Rh[(size_t)(k + 5) * 1024 + col]);
      u.w = pack2(Rh[(size_t)(k + 6) * 1024 + col], Rh[(size_t)(k + 7) * 1024 + col]);
      wl4[q * 512 + t] = u;
    }
  }

  float rbv[4];
#pragma unroll
  for (int g = 0; g < 4; ++g) rbv[g] = rb[h * 1024 + g * 256 + d];

  float c = 0.f, n = 0.f, m = 0.f;
  if (t < 256) { ypub[t] = __float2half(0.f); ypub[256 + t] = __float2half(0.f); }
  __syncthreads();

  int cur = 0;
  const __half* pg = gx + ((size_t)b * NHH + h) * 1024;
  float cx[4];
#pragma unroll
  for (int g = 0; g < 4; ++g) cx[g] = __half2float(pg[g * 256 + d]);
  const size_t out_base = ((size_t)b * SS) * EE + h * DHH + d;

  for (int st = 0; st < SS; ++st) {
    // prefetch next step's gate inputs
    const __half* pn = pg + ((st + 1 < SS) ? (size_t)(BB * NHH * 1024) : 0);
    __half nx[4];
#pragma unroll
    for (int g = 0; g < 4; ++g) nx[g] = pn[g * 256 + d];

    const uint4* yv = (const uint4*)(ypub + cur * 256) + (par << 4);
    float aA0 = 0.f, aB0 = 0.f, aA1 = 0.f, aB1 = 0.f;
    float aA2 = 0.f, aB2 = 0.f, aA3 = 0.f, aB3 = 0.f;
#pragma unroll
    for (int j = 0; j < 16; ++j) {
      uint4 yq = yv[j];                 // y dims kbase+8j .. kbase+8j+7
      uint4 wq = wl4[j * 512 + t];      // gate-3 weights, same k-range
      aA0 = fdot2u(wv[0][4 * j + 0], yq.x, aA0);
      aA1 = fdot2u(wv[1][4 * j + 0], yq.x, aA1);
      aA2 = fdot2u(wv[2][4 * j + 0], yq.x, aA2);
      aA3 = fdot2u(wq.x,             yq.x, aA3);
      aB0 = fdot2u(wv[0][4 * j + 1], yq.y, aB0);
      aB1 = fdot2u(wv[1][4 * j + 1], yq.y, aB1);
      aB2 = fdot2u(wv[2][4 * j + 1], yq.y, aB2);
      aB3 = fdot2u(wq.y,             yq.y, aB3);
      aA0 = fdot2u(wv[0][4 * j + 2], yq.z, aA0);
      aA1 = fdot2u(wv[1][4 * j + 2], yq.z, aA1);
      aA2 = fdot2u(wv[2][4 * j + 2], yq.z, aA2);
      aA3 = fdot2u(wq.z,             yq.z, aA3);
      aB0 = fdot2u(wv[0][4 * j + 3], yq.w, aB0);
      aB1 = fdot2u(wv[1][4 * j + 3], yq.w, aB1);
      aB2 = fdot2u(wv[2][4 * j + 3], yq.w, aB2);
      aB3 = fdot2u(wq.w,             yq.w, aB3);
    }

    // combine k-halves across the lane pair (even<->odd), all 4 gates
    float part0 = aA0 + aB0, part1 = aA1 + aB1;
    float part2 = aA2 + aB2, part3 = aA3 + aB3;
    float raw0 = part0 + __shfl_xor(part0, 1) + cx[0] + rbv[0];
    float raw1 = part1 + __shfl_xor(part1, 1) + cx[1] + rbv[1];
    float raw2 = part2 + __shfl_xor(part2, 1) + cx[2] + rbv[2];
    float raw3 = part3 + __shfl_xor(part3, 1) + cx[3] + rbv[3];

    // state update (redundant in both lanes of the pair)
    float iv = raw0, fv = raw1, zv = raw2, ov = raw3;
    float ea = __expf(-fabsf(fv));
    float ls = fminf(fv, 0.f) - __logf(1.f + ea);      // log_sigmoid(fv)
    float lfm = m + ls;
    float mn = fmaxf(iv, lfm);
    float ig = __expf(iv - mn);
    float fg = __expf(lfm - mn);
    float pz = __expf(-2.f * fabsf(zv));
    float tmag = __fdividef(1.f - pz, 1.f + pz);
    float th = (zv < 0.f) ? -tmag : tmag;              // tanh(zv)
    c = fg * c + ig * th;
    n = fg * n + ig;
    float og = __fdividef(1.f, 1.f + __expf(-ov));     // sigmoid(ov)
    float y = og * __fdividef(c, n);
    m = mn;

    if (par == 0) {
      out[out_base + (size_t)st * EE] = y;
      ypub[(cur ^ 1) * 256 + d] = __float2half(y);
    }
    __syncthreads();
    cur ^= 1;
    pg = pn;
#pragma unroll
    for (int g = 0; g < 4; ++g) cx[g] = __half2float(nx[g]);
  }
}

// ---------------------------------------------------------------------------
// GroupNorm over DH per (b,s,h), in place on out. One wave = one head.
// ---------------------------------------------------------------------------
__global__ __launch_bounds__(256) void groupnorm(
    float* __restrict__ y, const float* __restrict__ gnw)
{
  const int row = blockIdx.x;
  const int t = threadIdx.x;
  float4 v = ((const float4*)y)[(size_t)row * 256 + t];
  float s = v.x + v.y + v.z + v.w;
  float q = v.x * v.x + v.y * v.y + v.z * v.z + v.w * v.w;
#pragma unroll
  for (int mask = 1; mask < 64; mask <<= 1) {
    s += __shfl_xor(s, mask, 64);
    q += __shfl_xor(q, mask, 64);
  }
  float mu = s * (1.f / 256.f);
  float var = q * (1.f / 256.f) - mu * mu;
  float rs = rsqrtf(var + 1e-5f);
  float4 g = ((const float4*)gnw)[t];
  float4 o;
  o.x = (v.x - mu) * rs * g.x;
  o.y = (v.y - mu) * rs * g.y;
  o.z = (v.z - mu) * rs * g.z;
  o.w = (v.w - mu) * rs * g.w;
  ((float4*)y)[(size_t)row * 256 + t] = o;
}

extern "C" void kernel_launch(void* const* d_in, const int* in_sizes, int n_in,
                              void* d_out, int out_size, void* d_ws, size_t ws_size,
                              hipStream_t stream) {
  const float* x      = (const float*)d_in[0];
  const float* conv_w = (const float*)d_in[1];
  const float* conv_b = (const float*)d_in[2];
  const float* fgw    = (const float*)d_in[3];
  const float* igw    = (const float*)d_in[4];
  const float* zgw    = (const float*)d_in[5];
  const float* ogw    = (const float*)d_in[6];
  const float* rk     = (const float*)d_in[7];
  const float* rb     = (const float*)d_in[8];
  const float* gnw    = (const float*)d_in[9];
  float* out = (float*)d_out;
  __half* gx = (__half*)d_ws;   // [S][B][NH][1024] f16 = 134217728 B

  dim3 g1(256, 4, 4);
  gates_gemm2<<<g1, 256, 0, stream>>>(x, conv_w, conv_b, fgw, igw, zgw, ogw, gx);

  const int scan_lds = 131072 + 1024;
  (void)hipFuncSetAttribute(reinterpret_cast<const void*>(slstm_scan),
                            hipFuncAttributeMaxDynamicSharedMemorySize, scan_lds);
  slstm_scan<<<32, 512, scan_lds, stream>>>(rk, rb, gx, out);

  groupnorm<<<BB * SS, 256, 0, stream>>>(out, gnw);
}